// Round 2
// baseline (2313.400 us; speedup 1.0000x reference)
//
#include <hip/hip_runtime.h>

// ---------------------------------------------------------------------------
// GAT with heat-kernel diffusion preprocessing (GDC-style), MI355X fp32.
// Pipeline: CSR build -> 10x diffusion hops -> GEMM1+logits -> online-softmax
// GAT agg (8 heads x 8ch) -> ELU -> GEMM2+logits -> agg (1 head x 40ch) ->
// log_softmax.
// ---------------------------------------------------------------------------

__global__ void init_node_kernel(int* deg, int* cursor, int n) {
    int i = blockIdx.x * 256 + threadIdx.x;
    if (i < n) { deg[i] = 1; cursor[i] = 0; }  // deg starts at 1 (self loop)
}

__global__ void edge_deg_kernel(const int* __restrict__ dst, int* deg, int E) {
    int e = blockIdx.x * 256 + threadIdx.x;
    if (e < E) atomicAdd(&deg[dst[e]], 1);
}

// row_off via atomic segment allocation: each node gets a private contiguous
// range; ranges need not be ordered by node id for per-node iteration.
__global__ void alloc_kernel(const int* __restrict__ deg, float* dinv,
                             int* row_off, int* gcount, int n) {
    int i = blockIdx.x * 256 + threadIdx.x;
    if (i >= n) return;
    int dg = deg[i];
    dinv[i] = rsqrtf((float)dg);  // deg >= 1 always (self loop)
    row_off[i] = atomicAdd(gcount, dg);
}

__global__ void scatter_kernel(const int* __restrict__ ei, const int* __restrict__ row_off,
                               int* cursor, const float* __restrict__ dinv,
                               int* csr_src, float* csr_norm, int E, int n) {
    int e = blockIdx.x * 256 + threadIdx.x;
    if (e >= E + n) return;
    int s, d;
    if (e < E) { s = ei[e]; d = ei[E + e]; } else { s = e - E; d = s; }
    int pos = atomicAdd(&cursor[d], 1);
    int slot = row_off[d] + pos;
    csr_src[slot] = s;
    csr_norm[slot] = dinv[s] * dinv[d];
}

// coefs[k][c] = exp(-t_c) * t_c^k / k!
__global__ void coef_kernel(const float* __restrict__ t, float* coefs) {
    int c = threadIdx.x;  // 128 threads
    float tc = t[c];
    float v = expf(-tc);
    coefs[c] = v;
    for (int k = 1; k <= 10; ++k) { v *= tc / (float)k; coefs[k * 128 + c] = v; }
}

__global__ void init_diff_kernel(const float* __restrict__ x, const float* __restrict__ coefs,
                                 float* h, float* acc, int total) {
    int i = blockIdx.x * 256 + threadIdx.x;
    if (i >= total) return;
    float xv = x[i];
    h[i] = xv;
    acc[i] = coefs[i & 127] * xv;
}

// One wave per node. 128 channels = 2 per lane. h_next = A_hat * h;
// acc += coef_k * h_next (fused).
__global__ void hop_kernel(const int* __restrict__ row_off, const int* __restrict__ deg,
                           const int* __restrict__ csr_src, const float* __restrict__ csr_norm,
                           const float* __restrict__ h, float* __restrict__ h_next,
                           float* __restrict__ acc, const float* __restrict__ coefk, int n) {
    int wid = (blockIdx.x << 2) + (threadIdx.x >> 6);
    int lane = threadIdx.x & 63;
    if (wid >= n) return;
    int off = row_off[wid];
    int cnt = deg[wid];
    float s0 = 0.f, s1 = 0.f;
    for (int base = 0; base < cnt; base += 64) {
        int nb = min(64, cnt - base);
        int srcv = 0; float wv = 0.f;
        if (lane < nb) {
            srcv = csr_src[off + base + lane];
            wv = csr_norm[off + base + lane];
        }
        for (int tt = 0; tt < nb; ++tt) {
            int s = __shfl(srcv, tt);
            float w = __shfl(wv, tt);
            const float* hp = h + (size_t)s * 128;
            s0 = fmaf(w, hp[lane], s0);
            s1 = fmaf(w, hp[lane + 64], s1);
        }
    }
    size_t o = (size_t)wid * 128;
    h_next[o + lane] = s0;
    h_next[o + lane + 64] = s1;
    acc[o + lane]      = fmaf(coefk[lane],      s0, acc[o + lane]);
    acc[o + lane + 64] = fmaf(coefk[lane + 64], s1, acc[o + lane + 64]);
}

// h1 = acc @ W1 (128x64); fused per-head attention logits.
__global__ __launch_bounds__(256) void gemm1_kernel(
    const float* __restrict__ acc, const float* __restrict__ W1,
    const float* __restrict__ a_s, const float* __restrict__ a_d,
    float* __restrict__ h1, float* __restrict__ als, float* __restrict__ ald, int n) {
    __shared__ float Wl[128 * 64];
    for (int i = threadIdx.x; i < 128 * 64; i += 256) Wl[i] = W1[i];
    __syncthreads();
    int wid = (blockIdx.x << 2) + (threadIdx.x >> 6);
    int lane = threadIdx.x & 63;
    if (wid >= n) return;
    size_t o = (size_t)wid * 128;
    float r0 = acc[o + lane], r1 = acc[o + lane + 64];
    float sum = 0.f;
#pragma unroll
    for (int k = 0; k < 64; ++k) sum = fmaf(__shfl(r0, k), Wl[k * 64 + lane], sum);
#pragma unroll
    for (int k = 0; k < 64; ++k) sum = fmaf(__shfl(r1, k), Wl[(k + 64) * 64 + lane], sum);
    h1[(size_t)wid * 64 + lane] = sum;
    float vs = sum * a_s[lane];
    float vd = sum * a_d[lane];
    vs += __shfl_xor(vs, 1); vs += __shfl_xor(vs, 2); vs += __shfl_xor(vs, 4);
    vd += __shfl_xor(vd, 1); vd += __shfl_xor(vd, 2); vd += __shfl_xor(vd, 4);
    if ((lane & 7) == 0) {
        als[(size_t)wid * 8 + (lane >> 3)] = vs;
        ald[(size_t)wid * 8 + (lane >> 3)] = vd;
    }
}

// GAT layer-1 aggregation: online softmax per dst node, 8 heads x 8 channels,
// lane = head*8 + c. Then bias + ELU.
__global__ void agg1_kernel(const int* __restrict__ row_off, const int* __restrict__ deg,
                            const int* __restrict__ csr_src,
                            const float* __restrict__ h1, const float* __restrict__ als,
                            const float* __restrict__ ald, const float* __restrict__ b1,
                            float* __restrict__ helu, int n) {
    int wid = (blockIdx.x << 2) + (threadIdx.x >> 6);
    int lane = threadIdx.x & 63;
    if (wid >= n) return;
    int head = lane >> 3;
    int off = row_off[wid];
    int cnt = deg[wid];
    float aldv = ald[wid * 8 + head];
    float m = -1e30f, d = 0.f, accv = 0.f;
    for (int base = 0; base < cnt; base += 64) {
        int nb = min(64, cnt - base);
        int srcv = 0;
        if (lane < nb) srcv = csr_src[off + base + lane];
        for (int tt = 0; tt < nb; ++tt) {
            int s = __shfl(srcv, tt);
            float e = als[s * 8 + head] + aldv;
            e = e > 0.f ? e : 0.2f * e;  // leaky relu
            float mn = fmaxf(m, e);
            float scale = __expf(m - mn);
            float p = __expf(e - mn);
            float hv = h1[(size_t)s * 64 + lane];
            d = fmaf(d, scale, p);
            accv = fmaf(accv, scale, p * hv);
            m = mn;
        }
    }
    float outv = accv / d + b1[lane];
    outv = outv > 0.f ? outv : expm1f(outv);  // ELU
    helu[(size_t)wid * 64 + lane] = outv;
}

// h2 = helu @ W2 (64x40); fused scalar attention logits.
__global__ __launch_bounds__(256) void gemm2_kernel(
    const float* __restrict__ helu, const float* __restrict__ W2,
    const float* __restrict__ a_s, const float* __restrict__ a_d,
    float* __restrict__ h2, float* __restrict__ als, float* __restrict__ ald, int n) {
    __shared__ float Wl[64 * 40];
    for (int i = threadIdx.x; i < 64 * 40; i += 256) Wl[i] = W2[i];
    __syncthreads();
    int wid = (blockIdx.x << 2) + (threadIdx.x >> 6);
    int lane = threadIdx.x & 63;
    if (wid >= n) return;
    bool act = lane < 40;
    int li = act ? lane : 0;
    float r = helu[(size_t)wid * 64 + lane];
    float sum = 0.f;
#pragma unroll
    for (int k = 0; k < 64; ++k) sum = fmaf(__shfl(r, k), Wl[k * 40 + li], sum);
    if (act) h2[(size_t)wid * 40 + lane] = sum;
    float vs = act ? sum * a_s[lane] : 0.f;
    float vd = act ? sum * a_d[lane] : 0.f;
#pragma unroll
    for (int i = 32; i >= 1; i >>= 1) { vs += __shfl_xor(vs, i); vd += __shfl_xor(vd, i); }
    if (lane == 0) { als[wid] = vs; ald[wid] = vd; }
}

// GAT layer-2 aggregation (1 head, 40 ch) + bias + log_softmax.
__global__ void agg2_kernel(const int* __restrict__ row_off, const int* __restrict__ deg,
                            const int* __restrict__ csr_src,
                            const float* __restrict__ h2, const float* __restrict__ als,
                            const float* __restrict__ ald, const float* __restrict__ b2,
                            float* __restrict__ out, int n) {
    int wid = (blockIdx.x << 2) + (threadIdx.x >> 6);
    int lane = threadIdx.x & 63;
    if (wid >= n) return;
    bool act = lane < 40;
    int li = act ? lane : 0;
    int off = row_off[wid];
    int cnt = deg[wid];
    float aldv = ald[wid];
    float m = -1e30f, d = 0.f, accv = 0.f;
    for (int base = 0; base < cnt; base += 64) {
        int nb = min(64, cnt - base);
        int srcv = 0;
        if (lane < nb) srcv = csr_src[off + base + lane];
        for (int tt = 0; tt < nb; ++tt) {
            int s = __shfl(srcv, tt);
            float e = als[s] + aldv;
            e = e > 0.f ? e : 0.2f * e;
            float mn = fmaxf(m, e);
            float scale = __expf(m - mn);
            float p = __expf(e - mn);
            float hv = h2[(size_t)s * 40 + li];
            d = fmaf(d, scale, p);
            accv = fmaf(accv, scale, p * hv);
            m = mn;
        }
    }
    float o = accv / d + (act ? b2[lane] : 0.f);
    float vv = act ? o : -1e30f;
#pragma unroll
    for (int i = 32; i >= 1; i >>= 1) vv = fmaxf(vv, __shfl_xor(vv, i));
    float ex = act ? __expf(o - vv) : 0.f;
#pragma unroll
    for (int i = 32; i >= 1; i >>= 1) ex += __shfl_xor(ex, i);
    if (act) out[(size_t)wid * 40 + lane] = o - vv - logf(ex);
}

extern "C" void kernel_launch(void* const* d_in, const int* in_sizes, int n_in,
                              void* d_out, int out_size, void* d_ws, size_t ws_size,
                              hipStream_t stream) {
    const float* x    = (const float*)d_in[0];
    const int*   ei   = (const int*)d_in[1];
    const float* t    = (const float*)d_in[2];
    const float* W1   = (const float*)d_in[3];
    const float* a_s1 = (const float*)d_in[4];
    const float* a_d1 = (const float*)d_in[5];
    const float* b1   = (const float*)d_in[6];
    const float* W2   = (const float*)d_in[7];
    const float* a_s2 = (const float*)d_in[8];
    const float* a_d2 = (const float*)d_in[9];
    const float* b2   = (const float*)d_in[10];
    float* out = (float*)d_out;

    const int N = in_sizes[0] / 128;
    const int E = in_sizes[1] / 2;

    char* w = (char*)d_ws;
    auto carve = [&](size_t bytes) {
        void* p = (void*)w;
        w += (bytes + 255) & ~(size_t)255;
        return p;
    };
    int*   deg      = (int*)carve((size_t)N * 4);
    int*   cursor   = (int*)carve((size_t)N * 4);
    int*   row_off  = (int*)carve((size_t)N * 4);
    int*   gcount   = (int*)carve(256);
    float* dinv     = (float*)carve((size_t)N * 4);
    int*   csr_src  = (int*)carve((size_t)(E + N) * 4);
    float* csr_norm = (float*)carve((size_t)(E + N) * 4);
    float* coefs    = (float*)carve(11 * 128 * 4);
    float* als1     = (float*)carve((size_t)N * 8 * 4);
    float* ald1     = (float*)carve((size_t)N * 8 * 4);
    float* als2     = (float*)carve((size_t)N * 4);
    float* ald2     = (float*)carve((size_t)N * 4);
    float* hA       = (float*)carve((size_t)N * 128 * 4);
    float* hB       = (float*)carve((size_t)N * 128 * 4);
    float* acc      = (float*)carve((size_t)N * 128 * 4);
    // reuse diffusion ping-pong buffers after diffusion:
    float* h1   = hA;                     // [N,64]
    float* helu = hB;                     // [N,64]
    float* h2   = hA + (size_t)N * 64;    // [N,40] (disjoint from h1)

    dim3 blk(256);
    int gN = (N + 255) / 256;
    int gE = (E + 255) / 256;
    int gEN = (E + N + 255) / 256;
    int gW = (N + 3) / 4;  // one wave (64 lanes) per node, 4 waves/block

    init_node_kernel<<<gN, blk, 0, stream>>>(deg, cursor, N);
    hipMemsetAsync(gcount, 0, 4, stream);
    edge_deg_kernel<<<gE, blk, 0, stream>>>(ei + E, deg, E);
    alloc_kernel<<<gN, blk, 0, stream>>>(deg, dinv, row_off, gcount, N);
    scatter_kernel<<<gEN, blk, 0, stream>>>(ei, row_off, cursor, dinv, csr_src, csr_norm, E, N);
    coef_kernel<<<1, 128, 0, stream>>>(t, coefs);
    init_diff_kernel<<<(N * 128 + 255) / 256, blk, 0, stream>>>(x, coefs, hA, acc, N * 128);

    float* hc = hA;
    float* hn = hB;
    for (int k = 1; k <= 10; ++k) {
        hop_kernel<<<gW, blk, 0, stream>>>(row_off, deg, csr_src, csr_norm, hc, hn, acc,
                                           coefs + k * 128, N);
        float* tmp = hc; hc = hn; hn = tmp;
    }

    gemm1_kernel<<<gW, blk, 0, stream>>>(acc, W1, a_s1, a_d1, h1, als1, ald1, N);
    agg1_kernel<<<gW, blk, 0, stream>>>(row_off, deg, csr_src, h1, als1, ald1, b1, helu, N);
    gemm2_kernel<<<gW, blk, 0, stream>>>(helu, W2, a_s2, a_d2, h2, als2, ald2, N);
    agg2_kernel<<<gW, blk, 0, stream>>>(row_off, deg, csr_src, h2, als2, ald2, b2, out, N);
}